// Round 1
// baseline (829.984 us; speedup 1.0000x reference)
//
#include <hip/hip_runtime.h>
#include <hip/hip_bf16.h>

#define N_NODES 50000
#define N_EDGES 400000
#define IN_DIM_ 128
#define WIDTH_ 256
#define HEADS_ 4
#define HID_ 64
#define NUM_GRAPHS_ 256
#define NEG_SLOPE_ 0.2f

// ---------------- CSR build ----------------
__global__ void hist_kernel(const int* __restrict__ dst, int* __restrict__ deg) {
    int e = blockIdx.x * blockDim.x + threadIdx.x;
    if (e < N_EDGES) atomicAdd(&deg[dst[e]], 1);
}

__global__ void scan1_kernel(const int* __restrict__ deg, int* __restrict__ rowptr,
                             int* __restrict__ partials) {
    __shared__ int s[256];
    int t = threadIdx.x;
    int gid = blockIdx.x * 256 + t;
    int v = (gid < N_NODES) ? deg[gid] : 0;
    s[t] = v;
    __syncthreads();
    for (int off = 1; off < 256; off <<= 1) {
        int x = 0;
        if (t >= off) x = s[t - off];
        __syncthreads();
        if (t >= off) s[t] += x;
        __syncthreads();
    }
    if (gid < N_NODES) rowptr[gid] = s[t] - v;   // exclusive
    if (t == 255) partials[blockIdx.x] = s[255];
}

__global__ void scan2_kernel(int* __restrict__ partials, int nb) {
    __shared__ int s[256];
    int t = threadIdx.x;
    int v = (t < nb) ? partials[t] : 0;
    s[t] = v;
    __syncthreads();
    for (int off = 1; off < 256; off <<= 1) {
        int x = 0;
        if (t >= off) x = s[t - off];
        __syncthreads();
        if (t >= off) s[t] += x;
        __syncthreads();
    }
    if (t < nb) partials[t] = s[t] - v;          // exclusive
}

__global__ void scan3_kernel(int* __restrict__ rowptr, const int* __restrict__ partials) {
    int gid = blockIdx.x * 256 + threadIdx.x;
    if (gid < N_NODES) rowptr[gid] += partials[blockIdx.x];
    if (gid == 0) rowptr[N_NODES] = N_EDGES;
}

__global__ void scatter_kernel(const int* __restrict__ src, const int* __restrict__ dst,
                               const int* __restrict__ rowptr, int* __restrict__ cursor,
                               int* __restrict__ csr_src) {
    int e = blockIdx.x * blockDim.x + threadIdx.x;
    if (e < N_EDGES) {
        int d = dst[e];
        int pos = rowptr[d] + atomicAdd(&cursor[d], 1);
        csr_src[pos] = src[e];
    }
}

// ---------------- SGEMM: C[M,256] = A[M,K] @ B[K,256] ----------------
template <int K>
__global__ __launch_bounds__(256) void sgemm_kernel(const float* __restrict__ A,
                                                    const float* __restrict__ B,
                                                    float* __restrict__ C) {
    __shared__ float As[32][68];   // [k][m], padded: row stride 68 floats (16B-aligned)
    __shared__ float Bs[32][68];   // [k][n]
    const int tid = threadIdx.x;
    const int tx = tid & 15;       // n micro
    const int ty = tid >> 4;       // m micro
    const int row0 = blockIdx.x * 64;
    const int col0 = blockIdx.y * 64;

    float acc[4][4] = {};

    for (int kk = 0; kk < K; kk += 32) {
        // A tile: 64 rows x 32 k (512 float4 loads, 2 per thread), store transposed
#pragma unroll
        for (int q0 = 0; q0 < 2; ++q0) {
            int q = q0 * 256 + tid;
            int r = q >> 3;
            int kq = (q & 7) << 2;
            int grow = row0 + r;
            float4 v = make_float4(0.f, 0.f, 0.f, 0.f);
            if (grow < N_NODES) v = *(const float4*)&A[(size_t)grow * K + kk + kq];
            As[kq + 0][r] = v.x;
            As[kq + 1][r] = v.y;
            As[kq + 2][r] = v.z;
            As[kq + 3][r] = v.w;
        }
        // B tile: 32 k x 64 n
#pragma unroll
        for (int q0 = 0; q0 < 2; ++q0) {
            int q = q0 * 256 + tid;
            int kq = q >> 4;
            int nq = (q & 15) << 2;
            float4 v = *(const float4*)&B[(size_t)(kk + kq) * WIDTH_ + col0 + nq];
            *(float4*)&Bs[kq][nq] = v;
        }
        __syncthreads();
#pragma unroll
        for (int k = 0; k < 32; ++k) {
            float4 a = *(const float4*)&As[k][ty << 2];
            float4 b = *(const float4*)&Bs[k][tx << 2];
            float av[4] = {a.x, a.y, a.z, a.w};
            float bv[4] = {b.x, b.y, b.z, b.w};
#pragma unroll
            for (int i = 0; i < 4; ++i)
#pragma unroll
                for (int j = 0; j < 4; ++j) acc[i][j] += av[i] * bv[j];
        }
        __syncthreads();
    }
#pragma unroll
    for (int i = 0; i < 4; ++i) {
        int grow = row0 + (ty << 2) + i;
        if (grow < N_NODES) {
            float4 v = make_float4(acc[i][0], acc[i][1], acc[i][2], acc[i][3]);
            *(float4*)&C[(size_t)grow * WIDTH_ + col0 + (tx << 2)] = v;
        }
    }
}

// ---------------- attention logits: al_s/al_d [N,4] ----------------
__global__ void al_kernel(const float* __restrict__ hl, const float* __restrict__ a_src,
                          const float* __restrict__ a_dst, float* __restrict__ als,
                          float* __restrict__ ald) {
    int wid = (blockIdx.x * blockDim.x + threadIdx.x) >> 6;
    int lane = threadIdx.x & 63;
    if (wid >= N_NODES) return;
    const float4 hv = *(const float4*)&hl[(size_t)wid * WIDTH_ + (lane << 2)];
    int hd = lane >> 4;
    int j0 = (lane & 15) << 2;
    const float4 as = *(const float4*)&a_src[hd * HID_ + j0];
    const float4 ad = *(const float4*)&a_dst[hd * HID_ + j0];
    float ps = hv.x * as.x + hv.y * as.y + hv.z * as.z + hv.w * as.w;
    float pd = hv.x * ad.x + hv.y * ad.y + hv.z * ad.z + hv.w * ad.w;
    for (int off = 1; off < 16; off <<= 1) {
        ps += __shfl_xor(ps, off);
        pd += __shfl_xor(pd, off);
    }
    if ((lane & 15) == 0) {
        als[wid * 4 + hd] = ps;
        ald[wid * 4 + hd] = pd;
    }
}

// ---------------- per-dst-node online-softmax aggregation + bias + ELU ----------------
__global__ void aggregate_kernel(const float* __restrict__ hl, const float* __restrict__ als,
                                 const float* __restrict__ ald_, const int* __restrict__ rowptr,
                                 const int* __restrict__ csr_src, const float* __restrict__ bias,
                                 float* __restrict__ hout) {
    int n = (blockIdx.x * blockDim.x + threadIdx.x) >> 6;
    int lane = threadIdx.x & 63;
    if (n >= N_NODES) return;
    int hd = lane >> 4;
    int c0 = lane << 2;

    float ad = ald_[n * 4 + hd];
    // self loop first
    float e = als[n * 4 + hd] + ad;
    e = (e >= 0.f) ? e : NEG_SLOPE_ * e;
    float m = e;
    float denom = 1.0f;   // p_self = exp(e - m) = 1
    float4 hv = *(const float4*)&hl[(size_t)n * WIDTH_ + c0];
    float a0 = hv.x, a1 = hv.y, a2 = hv.z, a3 = hv.w;

    int rs = rowptr[n], re = rowptr[n + 1];
    for (int i = rs; i < re; ++i) {
        int s = csr_src[i];
        float es = als[s * 4 + hd] + ad;
        es = (es >= 0.f) ? es : NEG_SLOPE_ * es;
        float nm = fmaxf(m, es);
        float scale = expf(m - nm);
        float p = expf(es - nm);
        float4 hs = *(const float4*)&hl[(size_t)s * WIDTH_ + c0];
        a0 = a0 * scale + p * hs.x;
        a1 = a1 * scale + p * hs.y;
        a2 = a2 * scale + p * hs.z;
        a3 = a3 * scale + p * hs.w;
        denom = denom * scale + p;
        m = nm;
    }
    float inv = 1.0f / (denom + 1e-16f);
    float r0 = a0 * inv + bias[c0 + 0];
    float r1 = a1 * inv + bias[c0 + 1];
    float r2 = a2 * inv + bias[c0 + 2];
    float r3 = a3 * inv + bias[c0 + 3];
    // ELU
    r0 = (r0 > 0.f) ? r0 : (expf(r0) - 1.f);
    r1 = (r1 > 0.f) ? r1 : (expf(r1) - 1.f);
    r2 = (r2 > 0.f) ? r2 : (expf(r2) - 1.f);
    r3 = (r3 > 0.f) ? r3 : (expf(r3) - 1.f);
    float4 o = make_float4(r0, r1, r2, r3);
    *(float4*)&hout[(size_t)n * WIDTH_ + c0] = o;
}

// ---------------- final pool: out[g] = sum_{n in g} dot(h3[n], lin_w) + lin_b ----------------
__global__ void out_init_kernel(const float* __restrict__ lin_b, float* __restrict__ out) {
    out[threadIdx.x] = lin_b[0];
}

__global__ void pool_kernel(const float* __restrict__ h3, const float* __restrict__ lin_w,
                            const int* __restrict__ batch, float* __restrict__ out) {
    int n = (blockIdx.x * blockDim.x + threadIdx.x) >> 6;
    int lane = threadIdx.x & 63;
    if (n >= N_NODES) return;
    float4 hv = *(const float4*)&h3[(size_t)n * WIDTH_ + (lane << 2)];
    float4 wv = *(const float4*)&lin_w[lane << 2];
    float p = hv.x * wv.x + hv.y * wv.y + hv.z * wv.z + hv.w * wv.w;
    for (int off = 1; off < 64; off <<= 1) p += __shfl_xor(p, off);
    if (lane == 0) atomicAdd(&out[batch[n]], p);
}

extern "C" void kernel_launch(void* const* d_in, const int* in_sizes, int n_in,
                              void* d_out, int out_size, void* d_ws, size_t ws_size,
                              hipStream_t stream) {
    const float* x = (const float*)d_in[0];
    const int* edge_index = (const int*)d_in[1];
    const int* batch = (const int*)d_in[3];
    const float* W0 = (const float*)d_in[4];
    const float* a_src0 = (const float*)d_in[5];
    const float* a_dst0 = (const float*)d_in[6];
    const float* b0 = (const float*)d_in[7];
    const float* W1 = (const float*)d_in[8];
    const float* a_src1 = (const float*)d_in[9];
    const float* a_dst1 = (const float*)d_in[10];
    const float* b1 = (const float*)d_in[11];
    const float* W2 = (const float*)d_in[12];
    const float* a_src2 = (const float*)d_in[13];
    const float* a_dst2 = (const float*)d_in[14];
    const float* b2 = (const float*)d_in[15];
    const float* lin_w = (const float*)d_in[16];
    const float* lin_b = (const float*)d_in[17];
    float* out = (float*)d_out;

    const int* e_src = edge_index;
    const int* e_dst = edge_index + N_EDGES;

    // ---- workspace layout ----
    float* ws = (float*)d_ws;
    const size_t HROW = 50048;  // padded rows
    float* hA = ws;                               // GEMM output (hl)
    float* hB = hA + HROW * WIDTH_;               // aggregate output (layer input)
    float* als = hB + HROW * WIDTH_;              // [N,4]
    float* ald = als + HROW * 4;
    int* deg = (int*)(ald + HROW * 4);            // [N]
    int* rowptr = deg + 50048;                    // [N+1]
    int* cursor = rowptr + 50052;                 // [N]
    int* csr_src = cursor + 50048;                // [E]
    int* partials = csr_src + N_EDGES;            // [256]

    // ---- CSR build ----
    hipMemsetAsync(deg, 0, 50048 * sizeof(int), stream);
    hipMemsetAsync(cursor, 0, 50048 * sizeof(int), stream);
    hist_kernel<<<(N_EDGES + 255) / 256, 256, 0, stream>>>(e_dst, deg);
    const int NB1 = (N_NODES + 255) / 256;  // 196
    scan1_kernel<<<NB1, 256, 0, stream>>>(deg, rowptr, partials);
    scan2_kernel<<<1, 256, 0, stream>>>(partials, NB1);
    scan3_kernel<<<NB1, 256, 0, stream>>>(rowptr, partials);
    scatter_kernel<<<(N_EDGES + 255) / 256, 256, 0, stream>>>(e_src, e_dst, rowptr, cursor,
                                                              csr_src);

    // ---- layers ----
    dim3 ggrid((N_NODES + 63) / 64, WIDTH_ / 64);  // (782, 4)
    const int NWB = (N_NODES + 3) / 4;             // 12500 blocks of 4 waves

    // layer 0
    sgemm_kernel<IN_DIM_><<<ggrid, 256, 0, stream>>>(x, W0, hA);
    al_kernel<<<NWB, 256, 0, stream>>>(hA, a_src0, a_dst0, als, ald);
    aggregate_kernel<<<NWB, 256, 0, stream>>>(hA, als, ald, rowptr, csr_src, b0, hB);
    // layer 1
    sgemm_kernel<WIDTH_><<<ggrid, 256, 0, stream>>>(hB, W1, hA);
    al_kernel<<<NWB, 256, 0, stream>>>(hA, a_src1, a_dst1, als, ald);
    aggregate_kernel<<<NWB, 256, 0, stream>>>(hA, als, ald, rowptr, csr_src, b1, hB);
    // layer 2
    sgemm_kernel<WIDTH_><<<ggrid, 256, 0, stream>>>(hB, W2, hA);
    al_kernel<<<NWB, 256, 0, stream>>>(hA, a_src2, a_dst2, als, ald);
    aggregate_kernel<<<NWB, 256, 0, stream>>>(hA, als, ald, rowptr, csr_src, b2, hB);

    // ---- pool + linear ----
    out_init_kernel<<<1, 256, 0, stream>>>(lin_b, out);
    pool_kernel<<<NWB, 256, 0, stream>>>(hB, lin_w, batch, out);
}

// Round 2
// 794.642 us; speedup vs baseline: 1.0445x; 1.0445x over previous
//
#include <hip/hip_runtime.h>
#include <hip/hip_bf16.h>

#define N_NODES 50000
#define N_EDGES 400000
#define IN_DIM_ 128
#define WIDTH_ 256
#define HEADS_ 4
#define HID_ 64
#define NUM_GRAPHS_ 256
#define NEG_SLOPE_ 0.2f

// ---------------- CSR build ----------------
__global__ void hist_kernel(const int* __restrict__ dst, int* __restrict__ deg) {
    int e = blockIdx.x * blockDim.x + threadIdx.x;
    if (e < N_EDGES) atomicAdd(&deg[dst[e]], 1);
}

__global__ void scan1_kernel(const int* __restrict__ deg, int* __restrict__ rowptr,
                             int* __restrict__ partials) {
    __shared__ int s[256];
    int t = threadIdx.x;
    int gid = blockIdx.x * 256 + t;
    int v = (gid < N_NODES) ? deg[gid] : 0;
    s[t] = v;
    __syncthreads();
    for (int off = 1; off < 256; off <<= 1) {
        int x = 0;
        if (t >= off) x = s[t - off];
        __syncthreads();
        if (t >= off) s[t] += x;
        __syncthreads();
    }
    if (gid < N_NODES) rowptr[gid] = s[t] - v;   // exclusive
    if (t == 255) partials[blockIdx.x] = s[255];
}

__global__ void scan2_kernel(int* __restrict__ partials, int nb) {
    __shared__ int s[256];
    int t = threadIdx.x;
    int v = (t < nb) ? partials[t] : 0;
    s[t] = v;
    __syncthreads();
    for (int off = 1; off < 256; off <<= 1) {
        int x = 0;
        if (t >= off) x = s[t - off];
        __syncthreads();
        if (t >= off) s[t] += x;
        __syncthreads();
    }
    if (t < nb) partials[t] = s[t] - v;          // exclusive
}

__global__ void scan3_kernel(int* __restrict__ rowptr, const int* __restrict__ partials) {
    int gid = blockIdx.x * 256 + threadIdx.x;
    if (gid < N_NODES) rowptr[gid] += partials[blockIdx.x];
    if (gid == 0) rowptr[N_NODES] = N_EDGES;
}

__global__ void scatter_kernel(const int* __restrict__ src, const int* __restrict__ dst,
                               const int* __restrict__ rowptr, int* __restrict__ cursor,
                               int* __restrict__ csr_src) {
    int e = blockIdx.x * blockDim.x + threadIdx.x;
    if (e < N_EDGES) {
        int d = dst[e];
        int pos = rowptr[d] + atomicAdd(&cursor[d], 1);
        csr_src[pos] = src[e];
    }
}

// ---------------- SGEMM: C[M,256] = A[M,K] @ B[K,256] ----------------
// 128x128 tile, BK=16, 256 threads, 8x8 micro-tile (split-half: frags at
// ty*4 and 64+ty*4 so all ds_read_b128 are <=2-way bank aliased = free).
template <int K>
__global__ __launch_bounds__(256) void sgemm_kernel(const float* __restrict__ A,
                                                    const float* __restrict__ B,
                                                    float* __restrict__ C) {
    __shared__ float As[16][132];   // [k][m] transposed
    __shared__ float Bs[16][132];   // [k][n]
    const int tid = threadIdx.x;
    const int tx = tid & 15;        // n
    const int ty = tid >> 4;        // m
    const int row0 = blockIdx.x * 128;
    const int col0 = blockIdx.y * 128;

    float acc[8][8] = {};

    for (int kk = 0; kk < K; kk += 16) {
        // A tile: 128 rows x 16 k = 512 float4 loads (2/thread), store transposed
#pragma unroll
        for (int q0 = 0; q0 < 2; ++q0) {
            int q = q0 * 256 + tid;
            int r = q >> 2;                 // 0..127
            int kq = (q & 3) << 2;          // 0,4,8,12
            int grow = row0 + r;
            float4 v = make_float4(0.f, 0.f, 0.f, 0.f);
            if (grow < N_NODES) v = *(const float4*)&A[(size_t)grow * K + kk + kq];
            As[kq + 0][r] = v.x;
            As[kq + 1][r] = v.y;
            As[kq + 2][r] = v.z;
            As[kq + 3][r] = v.w;
        }
        // B tile: 16 k x 128 n = 512 float4 loads (2/thread)
#pragma unroll
        for (int q0 = 0; q0 < 2; ++q0) {
            int q = q0 * 256 + tid;
            int kq = q >> 5;                // 0..15
            int nq = (q & 31) << 2;         // 0..124
            float4 v = *(const float4*)&B[(size_t)(kk + kq) * WIDTH_ + col0 + nq];
            *(float4*)&Bs[kq][nq] = v;
        }
        __syncthreads();
#pragma unroll
        for (int k = 0; k < 16; ++k) {
            float4 a0 = *(const float4*)&As[k][ty << 2];
            float4 a1 = *(const float4*)&As[k][64 + (ty << 2)];
            float4 b0 = *(const float4*)&Bs[k][tx << 2];
            float4 b1 = *(const float4*)&Bs[k][64 + (tx << 2)];
            float av[8] = {a0.x, a0.y, a0.z, a0.w, a1.x, a1.y, a1.z, a1.w};
            float bv[8] = {b0.x, b0.y, b0.z, b0.w, b1.x, b1.y, b1.z, b1.w};
#pragma unroll
            for (int i = 0; i < 8; ++i)
#pragma unroll
                for (int j = 0; j < 8; ++j) acc[i][j] += av[i] * bv[j];
        }
        __syncthreads();
    }
#pragma unroll
    for (int i = 0; i < 8; ++i) {
        int grow = row0 + (i < 4 ? (ty << 2) + i : 64 + (ty << 2) + i - 4);
        if (grow < N_NODES) {
            float4 v0 = make_float4(acc[i][0], acc[i][1], acc[i][2], acc[i][3]);
            float4 v1 = make_float4(acc[i][4], acc[i][5], acc[i][6], acc[i][7]);
            *(float4*)&C[(size_t)grow * WIDTH_ + col0 + (tx << 2)] = v0;
            *(float4*)&C[(size_t)grow * WIDTH_ + col0 + 64 + (tx << 2)] = v1;
        }
    }
}

// ---------------- attention logits: al_s/al_d [N,4] ----------------
__global__ void al_kernel(const float* __restrict__ hl, const float* __restrict__ a_src,
                          const float* __restrict__ a_dst, float* __restrict__ als,
                          float* __restrict__ ald) {
    int wid = (blockIdx.x * blockDim.x + threadIdx.x) >> 6;
    int lane = threadIdx.x & 63;
    if (wid >= N_NODES) return;
    const float4 hv = *(const float4*)&hl[(size_t)wid * WIDTH_ + (lane << 2)];
    int hd = lane >> 4;
    int j0 = (lane & 15) << 2;
    const float4 as = *(const float4*)&a_src[hd * HID_ + j0];
    const float4 ad = *(const float4*)&a_dst[hd * HID_ + j0];
    float ps = hv.x * as.x + hv.y * as.y + hv.z * as.z + hv.w * as.w;
    float pd = hv.x * ad.x + hv.y * ad.y + hv.z * ad.z + hv.w * ad.w;
    for (int off = 1; off < 16; off <<= 1) {
        ps += __shfl_xor(ps, off);
        pd += __shfl_xor(pd, off);
    }
    if ((lane & 15) == 0) {
        als[wid * 4 + hd] = ps;
        ald[wid * 4 + hd] = pd;
    }
}

// ---------------- per-dst-node online-softmax aggregation + bias + ELU ----------------
__global__ void aggregate_kernel(const float* __restrict__ hl, const float* __restrict__ als,
                                 const float* __restrict__ ald_, const int* __restrict__ rowptr,
                                 const int* __restrict__ csr_src, const float* __restrict__ bias,
                                 float* __restrict__ hout) {
    int n = (blockIdx.x * blockDim.x + threadIdx.x) >> 6;
    int lane = threadIdx.x & 63;
    if (n >= N_NODES) return;
    int hd = lane >> 4;
    int c0 = lane << 2;

    float ad = ald_[n * 4 + hd];
    // self loop first
    float e = als[n * 4 + hd] + ad;
    e = (e >= 0.f) ? e : NEG_SLOPE_ * e;
    float m = e;
    float denom = 1.0f;   // p_self = exp(e - m) = 1
    float4 hv = *(const float4*)&hl[(size_t)n * WIDTH_ + c0];
    float a0 = hv.x, a1 = hv.y, a2 = hv.z, a3 = hv.w;

    int rs = rowptr[n], re = rowptr[n + 1];
    for (int i = rs; i < re; ++i) {
        int s = csr_src[i];
        float es = als[s * 4 + hd] + ad;
        es = (es >= 0.f) ? es : NEG_SLOPE_ * es;
        float nm = fmaxf(m, es);
        float scale = expf(m - nm);
        float p = expf(es - nm);
        float4 hs = *(const float4*)&hl[(size_t)s * WIDTH_ + c0];
        a0 = a0 * scale + p * hs.x;
        a1 = a1 * scale + p * hs.y;
        a2 = a2 * scale + p * hs.z;
        a3 = a3 * scale + p * hs.w;
        denom = denom * scale + p;
        m = nm;
    }
    float inv = 1.0f / (denom + 1e-16f);
    float r0 = a0 * inv + bias[c0 + 0];
    float r1 = a1 * inv + bias[c0 + 1];
    float r2 = a2 * inv + bias[c0 + 2];
    float r3 = a3 * inv + bias[c0 + 3];
    // ELU
    r0 = (r0 > 0.f) ? r0 : (expf(r0) - 1.f);
    r1 = (r1 > 0.f) ? r1 : (expf(r1) - 1.f);
    r2 = (r2 > 0.f) ? r2 : (expf(r2) - 1.f);
    r3 = (r3 > 0.f) ? r3 : (expf(r3) - 1.f);
    float4 o = make_float4(r0, r1, r2, r3);
    *(float4*)&hout[(size_t)n * WIDTH_ + c0] = o;
}

// ---------------- final pool ----------------
__global__ void out_init_kernel(const float* __restrict__ lin_b, float* __restrict__ out) {
    out[threadIdx.x] = lin_b[0];
}

// Block = 256 threads (4 waves) handles 64 contiguous nodes; per-node dot by a
// wave; lane0 accumulates into 256-slot LDS (batch is sorted -> ~1-2 graphs per
// block, LDS atomics are cheap); one global atomic per nonzero slot per block.
__global__ void pool_kernel(const float* __restrict__ h3, const float* __restrict__ lin_w,
                            const int* __restrict__ batch, float* __restrict__ out) {
    __shared__ float acc[NUM_GRAPHS_];
    int t = threadIdx.x;
    acc[t] = 0.f;
    __syncthreads();
    int wid = t >> 6, lane = t & 63;
    int n0 = blockIdx.x * 64;
    float4 wv = *(const float4*)&lin_w[lane << 2];
    for (int n = n0 + wid; n < n0 + 64; n += 4) {
        if (n >= N_NODES) break;
        float4 hv = *(const float4*)&h3[(size_t)n * WIDTH_ + (lane << 2)];
        float p = hv.x * wv.x + hv.y * wv.y + hv.z * wv.z + hv.w * wv.w;
        for (int off = 1; off < 64; off <<= 1) p += __shfl_xor(p, off);
        if (lane == 0) atomicAdd(&acc[batch[n]], p);
    }
    __syncthreads();
    float v = acc[t];
    if (v != 0.f) atomicAdd(&out[t], v);
}

extern "C" void kernel_launch(void* const* d_in, const int* in_sizes, int n_in,
                              void* d_out, int out_size, void* d_ws, size_t ws_size,
                              hipStream_t stream) {
    const float* x = (const float*)d_in[0];
    const int* edge_index = (const int*)d_in[1];
    const int* batch = (const int*)d_in[3];
    const float* W0 = (const float*)d_in[4];
    const float* a_src0 = (const float*)d_in[5];
    const float* a_dst0 = (const float*)d_in[6];
    const float* b0 = (const float*)d_in[7];
    const float* W1 = (const float*)d_in[8];
    const float* a_src1 = (const float*)d_in[9];
    const float* a_dst1 = (const float*)d_in[10];
    const float* b1 = (const float*)d_in[11];
    const float* W2 = (const float*)d_in[12];
    const float* a_src2 = (const float*)d_in[13];
    const float* a_dst2 = (const float*)d_in[14];
    const float* b2 = (const float*)d_in[15];
    const float* lin_w = (const float*)d_in[16];
    const float* lin_b = (const float*)d_in[17];
    float* out = (float*)d_out;

    const int* e_src = edge_index;
    const int* e_dst = edge_index + N_EDGES;

    // ---- workspace layout ----
    float* ws = (float*)d_ws;
    const size_t HROW = 50048;  // padded rows
    float* hA = ws;                               // GEMM output (hl)
    float* hB = hA + HROW * WIDTH_;               // aggregate output (layer input)
    float* als = hB + HROW * WIDTH_;              // [N,4]
    float* ald = als + HROW * 4;
    int* deg = (int*)(ald + HROW * 4);            // [N]
    int* rowptr = deg + 50048;                    // [N+1]
    int* cursor = rowptr + 50052;                 // [N]
    int* csr_src = cursor + 50048;                // [E]
    int* partials = csr_src + N_EDGES;            // [256]

    // ---- CSR build ----
    hipMemsetAsync(deg, 0, 50048 * sizeof(int), stream);
    hipMemsetAsync(cursor, 0, 50048 * sizeof(int), stream);
    hist_kernel<<<(N_EDGES + 255) / 256, 256, 0, stream>>>(e_dst, deg);
    const int NB1 = (N_NODES + 255) / 256;  // 196
    scan1_kernel<<<NB1, 256, 0, stream>>>(deg, rowptr, partials);
    scan2_kernel<<<1, 256, 0, stream>>>(partials, NB1);
    scan3_kernel<<<NB1, 256, 0, stream>>>(rowptr, partials);
    scatter_kernel<<<(N_EDGES + 255) / 256, 256, 0, stream>>>(e_src, e_dst, rowptr, cursor,
                                                              csr_src);

    // ---- layers ----
    dim3 ggrid((N_NODES + 127) / 128, WIDTH_ / 128);  // (391, 2)
    const int NWB = (N_NODES + 3) / 4;                // 12500 blocks of 4 waves

    // layer 0
    sgemm_kernel<IN_DIM_><<<ggrid, 256, 0, stream>>>(x, W0, hA);
    al_kernel<<<NWB, 256, 0, stream>>>(hA, a_src0, a_dst0, als, ald);
    aggregate_kernel<<<NWB, 256, 0, stream>>>(hA, als, ald, rowptr, csr_src, b0, hB);
    // layer 1
    sgemm_kernel<WIDTH_><<<ggrid, 256, 0, stream>>>(hB, W1, hA);
    al_kernel<<<NWB, 256, 0, stream>>>(hA, a_src1, a_dst1, als, ald);
    aggregate_kernel<<<NWB, 256, 0, stream>>>(hA, als, ald, rowptr, csr_src, b1, hB);
    // layer 2
    sgemm_kernel<WIDTH_><<<ggrid, 256, 0, stream>>>(hB, W2, hA);
    al_kernel<<<NWB, 256, 0, stream>>>(hA, a_src2, a_dst2, als, ald);
    aggregate_kernel<<<NWB, 256, 0, stream>>>(hA, als, ald, rowptr, csr_src, b2, hB);

    // ---- pool + linear ----
    out_init_kernel<<<1, 256, 0, stream>>>(lin_b, out);
    pool_kernel<<<(N_NODES + 63) / 64, 256, 0, stream>>>(hB, lin_w, batch, out);
}

// Round 5
// 602.414 us; speedup vs baseline: 1.3778x; 1.3191x over previous
//
#include <hip/hip_runtime.h>
#include <hip/hip_bf16.h>

#define N_NODES 50000
#define N_EDGES 400000
#define IN_DIM_ 128
#define WIDTH_ 256
#define HEADS_ 4
#define HID_ 64
#define NUM_GRAPHS_ 256
#define NEG_SLOPE_ 0.2f
#define HROW 50048  // padded rows (multiple of 128)

using s16x8 = __attribute__((ext_vector_type(8))) short;
using f32x4 = __attribute__((ext_vector_type(4))) float;

// split f32 into bf16 hi + bf16 lo (truncation; residual captured exactly)
__device__ inline void split1(float x, short& h, short& l) {
    unsigned int u = __float_as_uint(x);
    h = (short)(u >> 16);
    float hf = __uint_as_float(u & 0xffff0000u);
    float r = x - hf;  // exact
    l = (short)(__float_as_uint(r) >> 16);
}
__device__ inline float join1(short h, short l) {
    return __uint_as_float(((unsigned int)(unsigned short)h) << 16) +
           __uint_as_float(((unsigned int)(unsigned short)l) << 16);
}

// ---------------- CSR build ----------------
__global__ void hist_kernel(const int* __restrict__ dst, int* __restrict__ deg) {
    int e = blockIdx.x * blockDim.x + threadIdx.x;
    if (e < N_EDGES) atomicAdd(&deg[dst[e]], 1);
}

__global__ void scan1_kernel(const int* __restrict__ deg, int* __restrict__ rowptr,
                             int* __restrict__ partials) {
    __shared__ int s[256];
    int t = threadIdx.x;
    int gid = blockIdx.x * 256 + t;
    int v = (gid < N_NODES) ? deg[gid] : 0;
    s[t] = v;
    __syncthreads();
    for (int off = 1; off < 256; off <<= 1) {
        int x = 0;
        if (t >= off) x = s[t - off];
        __syncthreads();
        if (t >= off) s[t] += x;
        __syncthreads();
    }
    if (gid < N_NODES) rowptr[gid] = s[t] - v;
    if (t == 255) partials[blockIdx.x] = s[255];
}

__global__ void scan2_kernel(int* __restrict__ partials, int nb) {
    __shared__ int s[256];
    int t = threadIdx.x;
    int v = (t < nb) ? partials[t] : 0;
    s[t] = v;
    __syncthreads();
    for (int off = 1; off < 256; off <<= 1) {
        int x = 0;
        if (t >= off) x = s[t - off];
        __syncthreads();
        if (t >= off) s[t] += x;
        __syncthreads();
    }
    if (t < nb) partials[t] = s[t] - v;
}

__global__ void scan3_kernel(int* __restrict__ rowptr, const int* __restrict__ partials) {
    int gid = blockIdx.x * 256 + threadIdx.x;
    if (gid < N_NODES) rowptr[gid] += partials[blockIdx.x];
    if (gid == 0) rowptr[N_NODES] = N_EDGES;
}

__global__ void scatter_kernel(const int* __restrict__ src, const int* __restrict__ dst,
                               const int* __restrict__ rowptr, int* __restrict__ cursor,
                               int* __restrict__ csr_src) {
    int e = blockIdx.x * blockDim.x + threadIdx.x;
    if (e < N_EDGES) {
        int d = dst[e];
        int pos = rowptr[d] + atomicAdd(&cursor[d], 1);
        csr_src[pos] = src[e];
    }
}

// ---------------- input splits ----------------
// x (f32 [N,K]) -> hi/lo bf16, padded rows zeroed. One thread = 4 elements.
template <int K>
__global__ void split4_kernel(const float* __restrict__ in, short* __restrict__ hi,
                              short* __restrict__ lo) {
    int idx = blockIdx.x * blockDim.x + threadIdx.x;      // float4 index
    if (idx >= HROW * K / 4) return;
    int e0 = idx << 2;
    int row = e0 / K;
    float4 v = make_float4(0.f, 0.f, 0.f, 0.f);
    if (row < N_NODES) v = *(const float4*)&in[e0];
    short4 h, l;
    split1(v.x, h.x, l.x);
    split1(v.y, h.y, l.y);
    split1(v.z, h.z, l.z);
    split1(v.w, h.w, l.w);
    *(short4*)&hi[e0] = h;
    *(short4*)&lo[e0] = l;
}

// W (f32 [K,256]) -> Wt hi/lo (bf16 [256,K])
__global__ void wsplit_kernel(const float* __restrict__ W, short* __restrict__ Whi,
                              short* __restrict__ Wlo, int K) {
    int idx = blockIdx.x * blockDim.x + threadIdx.x;
    if (idx >= K * 256) return;
    int k = idx >> 8, n = idx & 255;
    short h, l;
    split1(W[idx], h, l);
    Whi[n * K + k] = h;
    Wlo[n * K + k] = l;
}

// ---------------- MFMA GEMM: C[M,256] = A[M,K] @ Wt[N,K]^T (bf16x3 split) ----
// 128x128 tile, 4 waves (2x2), each wave 64x64 via 4x4 grid of 16x16x32 MFMAs.
// No LDS, no barriers: frags loaded straight from global (A: L3, Wt: L2).
template <int K>
__global__ __launch_bounds__(256) void mfma_gemm(const short* __restrict__ Ahi,
                                                 const short* __restrict__ Alo,
                                                 const short* __restrict__ Bhi,
                                                 const short* __restrict__ Blo,
                                                 float* __restrict__ C) {
    const int tid = threadIdx.x;
    const int lane = tid & 63;
    const int wid = tid >> 6;
    const int wm = wid >> 1, wn = wid & 1;
    const int row0 = blockIdx.x * 128 + wm * 64;
    const int col0 = blockIdx.y * 128 + wn * 64;
    const int lr = lane & 15;
    const int lk = (lane >> 4) << 3;

    f32x4 acc[4][4] = {};

    for (int kk = 0; kk < K; kk += 32) {
        s16x8 ah[4], av[4], bh[4], bv[4];
#pragma unroll
        for (int r = 0; r < 4; ++r) {
            size_t ai = (size_t)(row0 + r * 16 + lr) * K + kk + lk;
            ah[r] = *(const s16x8*)&Ahi[ai];
            av[r] = *(const s16x8*)&Alo[ai];
            size_t bi = (size_t)(col0 + r * 16 + lr) * K + kk + lk;
            bh[r] = *(const s16x8*)&Bhi[bi];
            bv[r] = *(const s16x8*)&Blo[bi];
        }
#pragma unroll
        for (int i = 0; i < 4; ++i)
#pragma unroll
            for (int j = 0; j < 4; ++j) {
                acc[i][j] = __builtin_amdgcn_mfma_f32_16x16x32_bf16(ah[i], bh[j], acc[i][j], 0, 0, 0);
                acc[i][j] = __builtin_amdgcn_mfma_f32_16x16x32_bf16(ah[i], bv[j], acc[i][j], 0, 0, 0);
                acc[i][j] = __builtin_amdgcn_mfma_f32_16x16x32_bf16(av[i], bh[j], acc[i][j], 0, 0, 0);
            }
    }
    // C/D layout: col = lane&15, row = (lane>>4)*4 + reg
    const int rb = (lane >> 4) << 2;
#pragma unroll
    for (int i = 0; i < 4; ++i)
#pragma unroll
        for (int q = 0; q < 4; ++q) {
            int r = row0 + i * 16 + rb + q;
#pragma unroll
            for (int j = 0; j < 4; ++j)
                C[(size_t)r * WIDTH_ + col0 + j * 16 + lr] = acc[i][j][q];
        }
}

// ---------------- attention logits: al_s/al_d [N,4] ----------------
__global__ void al_kernel(const float* __restrict__ hl, const float* __restrict__ a_src,
                          const float* __restrict__ a_dst, float* __restrict__ als,
                          float* __restrict__ ald) {
    int wid = (blockIdx.x * blockDim.x + threadIdx.x) >> 6;
    int lane = threadIdx.x & 63;
    if (wid >= N_NODES) return;
    const float4 hv = *(const float4*)&hl[(size_t)wid * WIDTH_ + (lane << 2)];
    int hd = lane >> 4;
    int j0 = (lane & 15) << 2;
    const float4 as = *(const float4*)&a_src[hd * HID_ + j0];
    const float4 ad = *(const float4*)&a_dst[hd * HID_ + j0];
    float ps = hv.x * as.x + hv.y * as.y + hv.z * as.z + hv.w * as.w;
    float pd = hv.x * ad.x + hv.y * ad.y + hv.z * ad.z + hv.w * ad.w;
    for (int off = 1; off < 16; off <<= 1) {
        ps += __shfl_xor(ps, off);
        pd += __shfl_xor(pd, off);
    }
    if ((lane & 15) == 0) {
        als[wid * 4 + hd] = ps;
        ald[wid * 4 + hd] = pd;
    }
}

// ------- per-dst online-softmax aggregation + bias + ELU; writes hi/lo bf16 ----
__global__ void aggregate_kernel(const float* __restrict__ hl, const float* __restrict__ als,
                                 const float* __restrict__ ald_, const int* __restrict__ rowptr,
                                 const int* __restrict__ csr_src, const float* __restrict__ bias,
                                 short* __restrict__ ohi, short* __restrict__ olo) {
    int n = (blockIdx.x * blockDim.x + threadIdx.x) >> 6;
    int lane = threadIdx.x & 63;
    if (n >= N_NODES) return;
    int hd = lane >> 4;
    int c0 = lane << 2;

    float ad = ald_[n * 4 + hd];
    float e = als[n * 4 + hd] + ad;
    e = (e >= 0.f) ? e : NEG_SLOPE_ * e;
    float m = e;
    float denom = 1.0f;
    float4 hv = *(const float4*)&hl[(size_t)n * WIDTH_ + c0];
    float a0 = hv.x, a1 = hv.y, a2 = hv.z, a3 = hv.w;

    int rs = rowptr[n], re = rowptr[n + 1];
    for (int i = rs; i < re; ++i) {
        int s = csr_src[i];
        float es = als[s * 4 + hd] + ad;
        es = (es >= 0.f) ? es : NEG_SLOPE_ * es;
        float nm = fmaxf(m, es);
        float scale = expf(m - nm);
        float p = expf(es - nm);
        float4 hs = *(const float4*)&hl[(size_t)s * WIDTH_ + c0];
        a0 = a0 * scale + p * hs.x;
        a1 = a1 * scale + p * hs.y;
        a2 = a2 * scale + p * hs.z;
        a3 = a3 * scale + p * hs.w;
        denom = denom * scale + p;
        m = nm;
    }
    float inv = 1.0f / (denom + 1e-16f);
    float r0 = a0 * inv + bias[c0 + 0];
    float r1 = a1 * inv + bias[c0 + 1];
    float r2 = a2 * inv + bias[c0 + 2];
    float r3 = a3 * inv + bias[c0 + 3];
    r0 = (r0 > 0.f) ? r0 : (expf(r0) - 1.f);
    r1 = (r1 > 0.f) ? r1 : (expf(r1) - 1.f);
    r2 = (r2 > 0.f) ? r2 : (expf(r2) - 1.f);
    r3 = (r3 > 0.f) ? r3 : (expf(r3) - 1.f);
    short4 h, l;
    split1(r0, h.x, l.x);
    split1(r1, h.y, l.y);
    split1(r2, h.z, l.z);
    split1(r3, h.w, l.w);
    *(short4*)&ohi[(size_t)n * WIDTH_ + c0] = h;
    *(short4*)&olo[(size_t)n * WIDTH_ + c0] = l;
}

// ---------------- final pool ----------------
__global__ void out_init_kernel(const float* __restrict__ lin_b, float* __restrict__ out) {
    out[threadIdx.x] = lin_b[0];
}

__global__ void pool_kernel(const short* __restrict__ hhi, const short* __restrict__ hlo,
                            const float* __restrict__ lin_w, const int* __restrict__ batch,
                            float* __restrict__ out) {
    __shared__ float acc[NUM_GRAPHS_];
    int t = threadIdx.x;
    acc[t] = 0.f;
    __syncthreads();
    int wid = t >> 6, lane = t & 63;
    int n0 = blockIdx.x * 64;
    float4 wv = *(const float4*)&lin_w[lane << 2];
    for (int n = n0 + wid; n < n0 + 64; n += 4) {
        if (n >= N_NODES) break;
        short4 vh = *(const short4*)&hhi[(size_t)n * WIDTH_ + (lane << 2)];
        short4 vl = *(const short4*)&hlo[(size_t)n * WIDTH_ + (lane << 2)];
        float p = join1(vh.x, vl.x) * wv.x + join1(vh.y, vl.y) * wv.y +
                  join1(vh.z, vl.z) * wv.z + join1(vh.w, vl.w) * wv.w;
        for (int off = 1; off < 64; off <<= 1) p += __shfl_xor(p, off);
        if (lane == 0) atomicAdd(&acc[batch[n]], p);
    }
    __syncthreads();
    float v = acc[t];
    if (v != 0.f) atomicAdd(&out[t], v);
}

extern "C" void kernel_launch(void* const* d_in, const int* in_sizes, int n_in,
                              void* d_out, int out_size, void* d_ws, size_t ws_size,
                              hipStream_t stream) {
    const float* x = (const float*)d_in[0];
    const int* edge_index = (const int*)d_in[1];
    const int* batch = (const int*)d_in[3];
    const float* W0 = (const float*)d_in[4];
    const float* a_src0 = (const float*)d_in[5];
    const float* a_dst0 = (const float*)d_in[6];
    const float* b0 = (const float*)d_in[7];
    const float* W1 = (const float*)d_in[8];
    const float* a_src1 = (const float*)d_in[9];
    const float* a_dst1 = (const float*)d_in[10];
    const float* b1 = (const float*)d_in[11];
    const float* W2 = (const float*)d_in[12];
    const float* a_src2 = (const float*)d_in[13];
    const float* a_dst2 = (const float*)d_in[14];
    const float* b2 = (const float*)d_in[15];
    const float* lin_w = (const float*)d_in[16];
    const float* lin_b = (const float*)d_in[17];
    float* out = (float*)d_out;

    const int* e_src = edge_index;
    const int* e_dst = edge_index + N_EDGES;

    // ---- workspace layout ----
    char* p = (char*)d_ws;
    float* hA = (float*)p;                p += (size_t)HROW * WIDTH_ * 4;   // 51.25 MB
    short* hBhi = (short*)p;              p += (size_t)HROW * WIDTH_ * 2;   // 25.6 MB
    short* hBlo = (short*)p;              p += (size_t)HROW * WIDTH_ * 2;   // 25.6 MB
    short* Wt0h = (short*)p;              p += 256 * IN_DIM_ * 2;
    short* Wt0l = (short*)p;              p += 256 * IN_DIM_ * 2;
    short* Wt1h = (short*)p;              p += 256 * WIDTH_ * 2;
    short* Wt1l = (short*)p;              p += 256 * WIDTH_ * 2;
    short* Wt2h = (short*)p;              p += 256 * WIDTH_ * 2;
    short* Wt2l = (short*)p;              p += 256 * WIDTH_ * 2;
    float* als = (float*)p;               p += (size_t)HROW * 4 * 4;
    float* ald = (float*)p;               p += (size_t)HROW * 4 * 4;
    int* deg = (int*)p;                   p += HROW * 4;
    int* rowptr = (int*)p;                p += (HROW + 4) * 4;
    int* cursor = (int*)p;                p += HROW * 4;
    int* csr_src = (int*)p;               p += (size_t)N_EDGES * 4;
    int* partials = (int*)p;              p += 256 * 4;
    // x splits alias hBhi (dead before aggregate layer 0 writes hB)
    short* xhi = hBhi;
    short* xlo = hBhi + (size_t)HROW * IN_DIM_;

    // ---- CSR build ----
    hipMemsetAsync(deg, 0, HROW * sizeof(int), stream);
    hipMemsetAsync(cursor, 0, HROW * sizeof(int), stream);
    hist_kernel<<<(N_EDGES + 255) / 256, 256, 0, stream>>>(e_dst, deg);
    const int NB1 = (N_NODES + 255) / 256;
    scan1_kernel<<<NB1, 256, 0, stream>>>(deg, rowptr, partials);
    scan2_kernel<<<1, 256, 0, stream>>>(partials, NB1);
    scan3_kernel<<<NB1, 256, 0, stream>>>(rowptr, partials);
    scatter_kernel<<<(N_EDGES + 255) / 256, 256, 0, stream>>>(e_src, e_dst, rowptr, cursor,
                                                              csr_src);

    // ---- weight splits ----
    wsplit_kernel<<<IN_DIM_, 256, 0, stream>>>(W0, Wt0h, Wt0l, IN_DIM_);
    wsplit_kernel<<<WIDTH_, 256, 0, stream>>>(W1, Wt1h, Wt1l, WIDTH_);
    wsplit_kernel<<<WIDTH_, 256, 0, stream>>>(W2, Wt2h, Wt2l, WIDTH_);
    // ---- x split ----
    split4_kernel<IN_DIM_><<<(HROW * IN_DIM_ / 4 + 255) / 256, 256, 0, stream>>>(x, xhi, xlo);

    dim3 ggrid(HROW / 128, WIDTH_ / 128);  // (391, 2)
    const int NWB = (N_NODES + 3) / 4;

    // layer 0
    mfma_gemm<IN_DIM_><<<ggrid, 256, 0, stream>>>(xhi, xlo, Wt0h, Wt0l, hA);
    al_kernel<<<NWB, 256, 0, stream>>>(hA, a_src0, a_dst0, als, ald);
    aggregate_kernel<<<NWB, 256, 0, stream>>>(hA, als, ald, rowptr, csr_src, b0, hBhi, hBlo);
    // layer 1
    mfma_gemm<WIDTH_><<<ggrid, 256, 0, stream>>>(hBhi, hBlo, Wt1h, Wt1l, hA);
    al_kernel<<<NWB, 256, 0, stream>>>(hA, a_src1, a_dst1, als, ald);
    aggregate_kernel<<<NWB, 256, 0, stream>>>(hA, als, ald, rowptr, csr_src, b1, hBhi, hBlo);
    // layer 2
    mfma_gemm<WIDTH_><<<ggrid, 256, 0, stream>>>(hBhi, hBlo, Wt2h, Wt2l, hA);
    al_kernel<<<NWB, 256, 0, stream>>>(hA, a_src2, a_dst2, als, ald);
    aggregate_kernel<<<NWB, 256, 0, stream>>>(hA, als, ald, rowptr, csr_src, b2, hBhi, hBlo);

    // ---- pool + linear ----
    out_init_kernel<<<1, 256, 0, stream>>>(lin_b, out);
    pool_kernel<<<(N_NODES + 63) / 64, 256, 0, stream>>>(hBhi, hBlo, lin_w, batch, out);
}